// Round 2
// baseline (52860.028 us; speedup 1.0000x reference)
//
#include <hip/hip_runtime.h>
#include <math.h>

#define DIMX 512
#define NHEADS 8
#define DHE 64
#define NB 266
#define FFD 2048
#define OUTD 32
#define BATCH 4
#define SEQ 8192
#define NTOK 32768
#define NLAYER 6

// dn = 64^-0.25, ratio = 266^-0.5, 0.5*dn^2 = 0.0625
#define DN_F 0.35355339059327373f
#define RATIO_F 0.06131393f

__device__ __forceinline__ float gelu_f(float x) {
    float x3 = x * x * x;
    return 0.5f * x * (1.0f + tanhf(0.7978845608028654f * (x + 0.044715f * x3)));
}

__device__ __forceinline__ unsigned int fkey(float f) {
    unsigned int u = __float_as_uint(f);
    return (u & 0x80000000u) ? ~u : (u | 0x80000000u);
}
__device__ __forceinline__ float funkey(unsigned int k) {
    unsigned int u = (k & 0x80000000u) ? (k & 0x7fffffffu) : ~k;
    return __uint_as_float(u);
}

__global__ __launch_bounds__(256) void zero_kernel(float* __restrict__ p, int n) {
    int i = blockIdx.x * 256 + threadIdx.x;
    if (i < n) p[i] = 0.f;
}

// ---------------- LayerNorm: one wave per 512-float row ----------------
__global__ __launch_bounds__(256) void ln_kernel(const float* __restrict__ x,
                                                 const float* __restrict__ g,
                                                 const float* __restrict__ b,
                                                 float* __restrict__ out) {
    int row = blockIdx.x * 4 + (threadIdx.x >> 6);
    int lane = threadIdx.x & 63;
    const float4* xr = (const float4*)(x + (size_t)row * DIMX);
    float4 v0 = xr[lane];
    float4 v1 = xr[lane + 64];
    float sum = v0.x + v0.y + v0.z + v0.w + v1.x + v1.y + v1.z + v1.w;
#pragma unroll
    for (int off = 32; off; off >>= 1) sum += __shfl_xor(sum, off);
    float mu = sum * (1.0f / 512.0f);
    float var = (v0.x - mu) * (v0.x - mu) + (v0.y - mu) * (v0.y - mu) +
                (v0.z - mu) * (v0.z - mu) + (v0.w - mu) * (v0.w - mu) +
                (v1.x - mu) * (v1.x - mu) + (v1.y - mu) * (v1.y - mu) +
                (v1.z - mu) * (v1.z - mu) + (v1.w - mu) * (v1.w - mu);
#pragma unroll
    for (int off = 32; off; off >>= 1) var += __shfl_xor(var, off);
    float rstd = rsqrtf(var * (1.0f / 512.0f) + 1e-5f);
    const float4* g4 = (const float4*)g;
    const float4* b4 = (const float4*)b;
    float4* o4 = (float4*)(out + (size_t)row * DIMX);
    float4 gg = g4[lane], bb = b4[lane], r;
    r.x = (v0.x - mu) * rstd * gg.x + bb.x;
    r.y = (v0.y - mu) * rstd * gg.y + bb.y;
    r.z = (v0.z - mu) * rstd * gg.z + bb.z;
    r.w = (v0.w - mu) * rstd * gg.w + bb.w;
    o4[lane] = r;
    gg = g4[lane + 64]; bb = b4[lane + 64];
    r.x = (v1.x - mu) * rstd * gg.x + bb.x;
    r.y = (v1.y - mu) * rstd * gg.y + bb.y;
    r.z = (v1.z - mu) * rstd * gg.z + bb.z;
    r.w = (v1.w - mu) * rstd * gg.w + bb.w;
    o4[lane + 64] = r;
}

// ---------------- fp32 GEMM: 128x128 tile, 8x8 per thread ----------------
// C[M,N] = (DOACC? C : 0) + A[M,K]@B[K,N] + bias, optional gelu (before acc).
// Requires M%128==0, K%16==0, N%8==0.
template <int DOACC, int DOGELU>
__global__ __launch_bounds__(256) void gemm_kernel(const float* __restrict__ A,
                                                   const float* __restrict__ B,
                                                   const float* __restrict__ bias,
                                                   float* __restrict__ C,
                                                   int M, int N, int K) {
    __shared__ float As[16][132];
    __shared__ float Bs[16][132];
    int t = threadIdx.x;
    int tx = t & 15, ty = t >> 4;
    int m0 = blockIdx.x * 128;
    int n0 = blockIdx.y * 128;
    float c[8][8];
#pragma unroll
    for (int i = 0; i < 8; i++)
#pragma unroll
        for (int j = 0; j < 8; j++) c[i][j] = 0.f;

    int am = t >> 1;       // 0..127
    int ak = (t & 1) * 8;  // 0 or 8
    const float* Aptr = A + (size_t)(m0 + am) * K + ak;
    int bn = (t & 15) * 8;  // 0..120
    int bk = t >> 4;        // 0..15
    bool bvalid = (n0 + bn) < N;
    const float* Bptr = B + (size_t)bk * N + n0 + bn;

    for (int k0 = 0; k0 < K; k0 += 16) {
        float4 a0 = *(const float4*)(Aptr + k0);
        float4 a1 = *(const float4*)(Aptr + k0 + 4);
        As[ak + 0][am] = a0.x; As[ak + 1][am] = a0.y;
        As[ak + 2][am] = a0.z; As[ak + 3][am] = a0.w;
        As[ak + 4][am] = a1.x; As[ak + 5][am] = a1.y;
        As[ak + 6][am] = a1.z; As[ak + 7][am] = a1.w;
        float4 b0 = make_float4(0.f, 0.f, 0.f, 0.f);
        float4 b1v = make_float4(0.f, 0.f, 0.f, 0.f);
        if (bvalid) {
            const float* bp = Bptr + (size_t)k0 * N;
            b0 = *(const float4*)bp;
            b1v = *(const float4*)(bp + 4);
        }
        *(float4*)&Bs[bk][bn] = b0;
        *(float4*)&Bs[bk][bn + 4] = b1v;
        __syncthreads();
#pragma unroll
        for (int kk = 0; kk < 16; kk++) {
            float4 av0 = *(const float4*)&As[kk][ty * 4];
            float4 av1 = *(const float4*)&As[kk][64 + ty * 4];
            float4 bv0 = *(const float4*)&Bs[kk][tx * 4];
            float4 bv1 = *(const float4*)&Bs[kk][64 + tx * 4];
            float a_[8] = {av0.x, av0.y, av0.z, av0.w, av1.x, av1.y, av1.z, av1.w};
            float b_[8] = {bv0.x, bv0.y, bv0.z, bv0.w, bv1.x, bv1.y, bv1.z, bv1.w};
#pragma unroll
            for (int i = 0; i < 8; i++)
#pragma unroll
                for (int j = 0; j < 8; j++) c[i][j] += a_[i] * b_[j];
        }
        __syncthreads();
    }
#pragma unroll
    for (int ih = 0; ih < 2; ih++)
#pragma unroll
        for (int il = 0; il < 4; il++) {
            size_t row = (size_t)m0 + ih * 64 + ty * 4 + il;
#pragma unroll
            for (int jh = 0; jh < 2; jh++) {
                int colbase = n0 + jh * 64 + tx * 4;
                if (colbase < N) {
                    float* cp = C + row * N + colbase;
#pragma unroll
                    for (int jl = 0; jl < 4; jl++) {
                        float v = c[ih * 4 + il][jh * 4 + jl];
                        if (bias) v += bias[colbase + jl];
                        if (DOGELU) v = gelu_f(v);
                        if (DOACC) v += cp[jl];
                        cp[jl] = v;
                    }
                }
            }
        }
}

// ---------------- global max over key features (pass 1) ----------------
// Kf treated as flat rows of 64 floats (NTOK*NHEADS rows total).
__global__ __launch_bounds__(320) void kmax_kernel(const float* __restrict__ Kf,
                                                   const float* __restrict__ proj,
                                                   unsigned int* __restrict__ kmaxkey,
                                                   int rows_per_block) {
    int tid = threadIdx.x;
    float4 pr[16];
    if (tid < NB) {
#pragma unroll
        for (int j = 0; j < 16; j++) pr[j] = ((const float4*)proj)[tid * 16 + j];
    }
    float lmax = -3.0e38f;
    size_t r0 = (size_t)blockIdx.x * rows_per_block;
    for (int r = 0; r < rows_per_block; r++) {
        const float4* kr = (const float4*)(Kf + (r0 + r) * DHE);
        if (tid < NB) {
            float acc = 0.f;
#pragma unroll
            for (int j = 0; j < 16; j++) {
                float4 kv = kr[j];
                acc += kv.x * pr[j].x + kv.y * pr[j].y + kv.z * pr[j].z + kv.w * pr[j].w;
            }
            lmax = fmaxf(lmax, acc);
        }
    }
    lmax *= DN_F;  // dn > 0 so max commutes
#pragma unroll
    for (int off = 32; off; off >>= 1) lmax = fmaxf(lmax, __shfl_xor(lmax, off));
    __shared__ float wmax[5];
    if ((tid & 63) == 0) wmax[tid >> 6] = lmax;
    __syncthreads();
    if (tid == 0) {
        float bm = wmax[0];
        for (int w = 1; w < 5; w++) bm = fmaxf(bm, wmax[w]);
        atomicMax(kmaxkey, fkey(bm));
    }
}

// ------------- fused kp + ctx/ksum accumulation (per batch element) -------------
// Kf/Vf: [SEQ, 512] for this b. blockIdx.x = h*chunks + ch.
// CTX: [NHEADS, NB, DHE] for this b; KSUM: [NHEADS, NB] for this b.
__global__ __launch_bounds__(320) void ctx_kernel(const float* __restrict__ Kf,
                                                  const float* __restrict__ Vf,
                                                  const float* __restrict__ proj,
                                                  const unsigned int* __restrict__ kmaxkey,
                                                  float* __restrict__ CTX,
                                                  float* __restrict__ KSUM,
                                                  int chunks) {
    __shared__ float kps[NB];
    __shared__ float vrow[DHE];
    int tid = threadIdx.x;
    int h = blockIdx.x / chunks;
    int ch = blockIdx.x - h * chunks;
    float4 pr[16];
    if (tid < NB) {
#pragma unroll
        for (int j = 0; j < 16; j++) pr[j] = ((const float4*)proj)[tid * 16 + j];
    }
    float mx = funkey(*kmaxkey);
    float cacc[54];
#pragma unroll
    for (int k = 0; k < 54; k++) cacc[k] = 0.f;
    float ksum_r = 0.f;
    int w = tid >> 6, d = tid & 63;
    int ntk = SEQ / chunks;
    int nbase = ch * ntk;
    for (int n = 0; n < ntk; n++) {
        size_t tg = (size_t)(nbase + n);
        const float4* kr = (const float4*)(Kf + tg * DIMX + h * DHE);
        if (tid < NB) {
            float acc = 0.f, ss = 0.f;
#pragma unroll
            for (int j = 0; j < 16; j++) {
                float4 kv = kr[j];
                acc += kv.x * pr[j].x + kv.y * pr[j].y + kv.z * pr[j].z + kv.w * pr[j].w;
                ss += kv.x * kv.x + kv.y * kv.y + kv.z * kv.z + kv.w * kv.w;
            }
            float kp = RATIO_F * (expf(acc * DN_F - ss * 0.0625f - mx) + 1e-4f);
            kps[tid] = kp;
            ksum_r += kp;
        }
        if (tid < 16)
            ((float4*)vrow)[tid] = ((const float4*)(Vf + tg * DIMX + h * DHE))[tid];
        __syncthreads();
        float vv = vrow[d];
#pragma unroll
        for (int k = 0; k < 54; k++) {
            int m = w + 5 * k;
            if (m < NB) cacc[k] += kps[m] * vv;
        }
        __syncthreads();
    }
    float* ctxp = CTX + (size_t)h * (NB * DHE);
#pragma unroll
    for (int k = 0; k < 54; k++) {
        int m = w + 5 * k;
        if (m < NB) atomicAdd(&ctxp[m * DHE + d], cacc[k]);
    }
    if (tid < NB) atomicAdd(&KSUM[(size_t)h * NB + tid], ksum_r);
}

// ------------- fused qp + o = d_inv * (qp @ ctx) (per batch element) -------------
// Qf: [SEQ,512] this b. Of: [SEQ,512] this b. CTX/KSUM: this b.
__global__ __launch_bounds__(320) void o_kernel(const float* __restrict__ Qf,
                                                const float* __restrict__ proj,
                                                const float* __restrict__ CTX,
                                                const float* __restrict__ KSUM,
                                                float* __restrict__ Of,
                                                int chunks) {
    __shared__ float qps[NB];
    __shared__ float redm[5];
    __shared__ float reds[5];
    __shared__ float opart[5][DHE];
    int tid = threadIdx.x;
    int h = blockIdx.x / chunks;
    int ch = blockIdx.x - h * chunks;
    float4 pr[16];
    if (tid < NB) {
#pragma unroll
        for (int j = 0; j < 16; j++) pr[j] = ((const float4*)proj)[tid * 16 + j];
    }
    int w = tid >> 6, d = tid & 63;
    float creg[54];
#pragma unroll
    for (int k = 0; k < 54; k++) {
        int m = w + 5 * k;
        creg[k] = (m < NB) ? CTX[(size_t)h * (NB * DHE) + m * DHE + d] : 0.f;
    }
    float ksum_r = (tid < NB) ? KSUM[(size_t)h * NB + tid] : 0.f;
    int ntk = SEQ / chunks;
    int nbase = ch * ntk;
    for (int n = 0; n < ntk; n++) {
        size_t tg = (size_t)(nbase + n);
        const float4* qr = (const float4*)(Qf + tg * DIMX + h * DHE);
        float xp = -3.0e38f, ss = 0.f;
        if (tid < NB) {
            float acc = 0.f;
#pragma unroll
            for (int j = 0; j < 16; j++) {
                float4 qv = qr[j];
                acc += qv.x * pr[j].x + qv.y * pr[j].y + qv.z * pr[j].z + qv.w * pr[j].w;
                ss += qv.x * qv.x + qv.y * qv.y + qv.z * qv.z + qv.w * qv.w;
            }
            xp = acc * DN_F;
        }
        float lm = xp;
#pragma unroll
        for (int off = 32; off; off >>= 1) lm = fmaxf(lm, __shfl_xor(lm, off));
        if ((tid & 63) == 0) redm[w] = lm;
        __syncthreads();
        float rmax = fmaxf(fmaxf(fmaxf(redm[0], redm[1]), fmaxf(redm[2], redm[3])), redm[4]);
        float dp = 0.f;
        if (tid < NB) {
            float qp = RATIO_F * (expf(xp - ss * 0.0625f - rmax) + 1e-4f);
            qps[tid] = qp;
            dp = qp * ksum_r;
        }
#pragma unroll
        for (int off = 32; off; off >>= 1) dp += __shfl_xor(dp, off);
        if ((tid & 63) == 0) reds[w] = dp;
        __syncthreads();
        float denom = reds[0] + reds[1] + reds[2] + reds[3] + reds[4];
        float dinv = 1.0f / denom;
        float op = 0.f;
#pragma unroll
        for (int k = 0; k < 54; k++) {
            int m = w + 5 * k;
            if (m < NB) op += qps[m] * creg[k];
        }
        opart[w][d] = op;
        __syncthreads();
        if (tid < DHE) {
            float o = opart[0][tid] + opart[1][tid] + opart[2][tid] + opart[3][tid] +
                      opart[4][tid];
            Of[tg * DIMX + h * DHE + tid] = o * dinv;
        }
        __syncthreads();
    }
}

extern "C" void kernel_launch(void* const* d_in, const int* in_sizes, int n_in,
                              void* d_out, int out_size, void* d_ws, size_t ws_size,
                              hipStream_t stream) {
    (void)in_sizes; (void)n_in; (void)out_size; (void)ws_size;
    const float* src  = (const float*)d_in[0];
    const float* proj = (const float*)d_in[1];
    const float* ln1g = (const float*)d_in[2];
    const float* ln1b = (const float*)d_in[3];
    const float* Wq   = (const float*)d_in[4];
    const float* Wk   = (const float*)d_in[5];
    const float* Wv   = (const float*)d_in[6];
    const float* Wo   = (const float*)d_in[7];
    const float* bo   = (const float*)d_in[8];
    const float* ln2g = (const float*)d_in[9];
    const float* ln2b = (const float*)d_in[10];
    const float* W1   = (const float*)d_in[11];
    const float* b1   = (const float*)d_in[12];
    const float* W2   = (const float*)d_in[13];
    const float* b2   = (const float*)d_in[14];
    const float* fcw  = (const float*)d_in[15];
    const float* fcb  = (const float*)d_in[16];
    float* out = (float*)d_out;

    // Lean workspace layout (~162 MiB):
    const size_t TD = (size_t)NTOK * DIMX;  // 16,777,216 floats (64 MiB)
    const size_t SD = (size_t)SEQ * DIMX;   //  4,194,304 floats (16 MiB)
    float* X    = (float*)d_ws;       // residual, full batch
    float* B1   = X + TD;             // full-batch K / O / FF-hidden
    float* Hs   = B1 + TD;            // per-b LN output
    float* B2s  = Hs + SD;            // per-b V / Q
    float* CTXb = B2s + SD;           // 32 * NB * DHE
    float* KSUMb = CTXb + 32 * NB * DHE;  // 32 * NB
    unsigned int* KMAX = (unsigned int*)(KSUMb + 32 * NB);
    const int nzero = 32 * NB * DHE + 32 * NB + 1;

    hipMemcpyAsync(X, src, sizeof(float) * TD, hipMemcpyDeviceToDevice, stream);

    dim3 gSeq(SEQ / 128, DIMX / 128);   // (64,4) per-b projection gemm
    for (int L = 0; L < NLAYER; L++) {
        const float* pj = proj + (size_t)L * NB * DHE;
        // --- pass 1: K for all b (into B1), then global key max ---
        for (int b = 0; b < BATCH; b++) {
            const float* Xb = X + (size_t)b * SD;
            float* Kb = B1 + (size_t)b * SD;
            ln_kernel<<<SEQ / 4, 256, 0, stream>>>(Xb, ln1g + L * DIMX, ln1b + L * DIMX, Hs);
            gemm_kernel<0, 0><<<gSeq, 256, 0, stream>>>(Hs, Wk + (size_t)L * DIMX * DIMX, nullptr, Kb, SEQ, DIMX, DIMX);
        }
        zero_kernel<<<(nzero + 255) / 256, 256, 0, stream>>>(CTXb, nzero);
        kmax_kernel<<<1024, 320, 0, stream>>>(B1, pj, KMAX, (NTOK * NHEADS) / 1024);
        // --- pass 2: per-b attention + Wo ---
        for (int b = 0; b < BATCH; b++) {
            const float* Xb = X + (size_t)b * SD;
            float* Kb = B1 + (size_t)b * SD;      // holds K_b, becomes O_b
            float* CTXp = CTXb + (size_t)b * NHEADS * NB * DHE;
            float* KSUMp = KSUMb + (size_t)b * NHEADS * NB;
            ln_kernel<<<SEQ / 4, 256, 0, stream>>>(Xb, ln1g + L * DIMX, ln1b + L * DIMX, Hs);
            gemm_kernel<0, 0><<<gSeq, 256, 0, stream>>>(Hs, Wv + (size_t)L * DIMX * DIMX, nullptr, B2s, SEQ, DIMX, DIMX);
            ctx_kernel<<<NHEADS * 32, 320, 0, stream>>>(Kb, B2s, pj, KMAX, CTXp, KSUMp, 32);
            gemm_kernel<0, 0><<<gSeq, 256, 0, stream>>>(Hs, Wq + (size_t)L * DIMX * DIMX, nullptr, B2s, SEQ, DIMX, DIMX);
            o_kernel<<<NHEADS * 32, 320, 0, stream>>>(B2s, pj, CTXp, KSUMp, Kb, 32);
            gemm_kernel<1, 0><<<gSeq, 256, 0, stream>>>(Kb, Wo + (size_t)L * DIMX * DIMX, bo + L * DIMX, (float*)Xb, SEQ, DIMX, DIMX);
        }
        // --- FF, per b, hidden in B1 ---
        for (int b = 0; b < BATCH; b++) {
            float* Xb = X + (size_t)b * SD;
            ln_kernel<<<SEQ / 4, 256, 0, stream>>>(Xb, ln2g + L * DIMX, ln2b + L * DIMX, Hs);
            gemm_kernel<0, 1><<<dim3(SEQ / 128, FFD / 128), 256, 0, stream>>>(
                Hs, W1 + (size_t)L * DIMX * FFD, b1 + L * FFD, B1, SEQ, FFD, DIMX);
            gemm_kernel<1, 0><<<dim3(SEQ / 128, DIMX / 128), 256, 0, stream>>>(
                B1, W2 + (size_t)L * FFD * DIMX, b2 + L * DIMX, Xb, SEQ, DIMX, FFD);
        }
    }
    gemm_kernel<0, 0><<<dim3(NTOK / 128, 1), 256, 0, stream>>>(X, fcw, fcb, out, NTOK, OUTD, DIMX);
}

// Round 3
// 34965.024 us; speedup vs baseline: 1.5118x; 1.5118x over previous
//
#include <hip/hip_runtime.h>
#include <math.h>

#define DIMX 512
#define NHEADS 8
#define DHE 64
#define NB 266
#define FFD 2048
#define OUTD 32
#define BATCH 4
#define SEQ 8192
#define NTOK 32768
#define NLAYER 6

#define DN_F 0.35355339059327373f
#define RATIO_F 0.06131393f

typedef unsigned short ushort_t;
typedef __attribute__((ext_vector_type(8))) short short8;
typedef __attribute__((ext_vector_type(4))) float floatx4;

__device__ __forceinline__ float gelu_f(float x) {
    float x3 = x * x * x;
    return 0.5f * x * (1.0f + tanhf(0.7978845608028654f * (x + 0.044715f * x3)));
}

__device__ __forceinline__ ushort_t f2bf(float f) {
    unsigned int u = __float_as_uint(f);
    unsigned int r = (u + 0x7fffu + ((u >> 16) & 1u)) >> 16;
    return (ushort_t)r;
}

__device__ __forceinline__ unsigned int fkey(float f) {
    unsigned int u = __float_as_uint(f);
    return (u & 0x80000000u) ? ~u : (u | 0x80000000u);
}
__device__ __forceinline__ float funkey(unsigned int k) {
    unsigned int u = (k & 0x80000000u) ? (k & 0x7fffffffu) : ~k;
    return __uint_as_float(u);
}

// async global->LDS 16B per lane; LDS dest = wave-uniform base + lane*16
__device__ __forceinline__ void gl_lds16(const void* g, void* l) {
    __builtin_amdgcn_global_load_lds(
        (const __attribute__((address_space(1))) unsigned int*)g,
        (__attribute__((address_space(3))) unsigned int*)l, 16, 0, 0);
}

__global__ __launch_bounds__(256) void zero_kernel(float* __restrict__ p, int n) {
    int i = blockIdx.x * 256 + threadIdx.x;
    if (i < n) p[i] = 0.f;
}

// ---------------- LayerNorm -> bf16 out: one wave per 512-float row ----------------
__global__ __launch_bounds__(256) void ln_bf16_kernel(const float* __restrict__ x,
                                                      const float* __restrict__ g,
                                                      const float* __restrict__ b,
                                                      ushort_t* __restrict__ out) {
    int row = blockIdx.x * 4 + (threadIdx.x >> 6);
    int lane = threadIdx.x & 63;
    const float4* xr = (const float4*)(x + (size_t)row * DIMX);
    float4 v0 = xr[lane];
    float4 v1 = xr[lane + 64];
    float sum = v0.x + v0.y + v0.z + v0.w + v1.x + v1.y + v1.z + v1.w;
#pragma unroll
    for (int off = 32; off; off >>= 1) sum += __shfl_xor(sum, off);
    float mu = sum * (1.0f / 512.0f);
    float var = (v0.x - mu) * (v0.x - mu) + (v0.y - mu) * (v0.y - mu) +
                (v0.z - mu) * (v0.z - mu) + (v0.w - mu) * (v0.w - mu) +
                (v1.x - mu) * (v1.x - mu) + (v1.y - mu) * (v1.y - mu) +
                (v1.z - mu) * (v1.z - mu) + (v1.w - mu) * (v1.w - mu);
#pragma unroll
    for (int off = 32; off; off >>= 1) var += __shfl_xor(var, off);
    float rstd = rsqrtf(var * (1.0f / 512.0f) + 1e-5f);
    const float4* g4 = (const float4*)g;
    const float4* b4 = (const float4*)b;
    ushort_t* orow = out + (size_t)row * DIMX;
    float4 gg = g4[lane], bb = b4[lane];
    ushort4 o;
    o.x = f2bf((v0.x - mu) * rstd * gg.x + bb.x);
    o.y = f2bf((v0.y - mu) * rstd * gg.y + bb.y);
    o.z = f2bf((v0.z - mu) * rstd * gg.z + bb.z);
    o.w = f2bf((v0.w - mu) * rstd * gg.w + bb.w);
    *(ushort4*)(orow + lane * 4) = o;
    gg = g4[lane + 64]; bb = b4[lane + 64];
    o.x = f2bf((v1.x - mu) * rstd * gg.x + bb.x);
    o.y = f2bf((v1.y - mu) * rstd * gg.y + bb.y);
    o.z = f2bf((v1.z - mu) * rstd * gg.z + bb.z);
    o.w = f2bf((v1.w - mu) * rstd * gg.w + bb.w);
    *(ushort4*)(orow + 256 + lane * 4) = o;
}

// ---------------- weight transpose-convert: W[K,N] fp32 -> Wt[N,K] bf16 ----------------
// grid (N/32, K/32), block 256 (32x8)
__global__ __launch_bounds__(256) void wconv_kernel(const float* __restrict__ W,
                                                    ushort_t* __restrict__ Wt,
                                                    int K, int N) {
    __shared__ float tile[32][33];
    int bx = blockIdx.x * 32;  // n
    int by = blockIdx.y * 32;  // k
    int tx = threadIdx.x & 31, ty = threadIdx.x >> 5;
#pragma unroll
    for (int r = 0; r < 4; r++)
        tile[ty + r * 8][tx] = W[(size_t)(by + ty + r * 8) * N + bx + tx];
    __syncthreads();
#pragma unroll
    for (int r = 0; r < 4; r++)
        Wt[(size_t)(bx + ty + r * 8) * K + by + tx] = f2bf(tile[tx][ty + r * 8]);
}

// ---------------- bf16 MFMA GEMM: 128x128 tile, 16x16x32, m97 structure ----------------
// A[M,K] bf16 row-major; Bt[N,K] bf16 row-major (i.e. B transposed).
// EPI 0: C = A@B (fp32). EPI 1: C += A@B + bias (fp32). EPI 2: Cb = bf16(gelu(A@B + bias)).
template <int EPI>
__global__ __launch_bounds__(256) void gemm_mfma(const ushort_t* __restrict__ A,
                                                 const ushort_t* __restrict__ Bt,
                                                 const float* __restrict__ bias,
                                                 float* __restrict__ C,
                                                 ushort_t* __restrict__ Cb,
                                                 int M, int N, int K) {
    __shared__ ushort_t As[128 * 32];
    __shared__ ushort_t Bs[128 * 32];
    int t = threadIdx.x;
    int wave = t >> 6, lane = t & 63;
    int wm = wave >> 1, wn = wave & 1;
    int m0 = blockIdx.x * 128, n0 = blockIdx.y * 128;
    int q = lane >> 4, ml = lane & 15;

    floatx4 acc[4][4];
#pragma unroll
    for (int i = 0; i < 4; i++)
#pragma unroll
        for (int j = 0; j < 4; j++) acc[i][j] = (floatx4)(0.f);

    // staging: wave w covers rows w*32..w*32+31 (2 instrs of 16 rows each);
    // lane l -> row (l>>2), col (l&3)*8 within the 16-row group. LDS [row][k], 32 bf16/row.
    int srow = (lane >> 2);
    int scol = (lane & 3) * 8;
    const ushort_t* Ag = A + (size_t)(m0 + wave * 32 + srow) * K + scol;
    const ushort_t* Bg = Bt + (size_t)(n0 + wave * 32 + srow) * K + scol;
    ushort_t* AsW = &As[(wave * 32) * 32];
    ushort_t* BsW = &Bs[(wave * 32) * 32];

    for (int k0 = 0; k0 < K; k0 += 32) {
        gl_lds16(Ag + k0, AsW);
        gl_lds16(Ag + k0 + (size_t)16 * K, AsW + 16 * 32);
        gl_lds16(Bg + k0, BsW);
        gl_lds16(Bg + k0 + (size_t)16 * K, BsW + 16 * 32);
        __syncthreads();  // drains vmcnt before barrier
        short8 a[4], b[4];
#pragma unroll
        for (int i = 0; i < 4; i++)
            a[i] = *(const short8*)&As[(wm * 64 + i * 16 + ml) * 32 + q * 8];
#pragma unroll
        for (int j = 0; j < 4; j++)
            b[j] = *(const short8*)&Bs[(wn * 64 + j * 16 + ml) * 32 + q * 8];
#pragma unroll
        for (int i = 0; i < 4; i++)
#pragma unroll
            for (int j = 0; j < 4; j++)
                acc[i][j] = __builtin_amdgcn_mfma_f32_16x16x32_bf16(a[i], b[j], acc[i][j], 0, 0, 0);
        __syncthreads();
    }

    // C/D layout: col = lane&15, row = (lane>>4)*4 + reg
#pragma unroll
    for (int i = 0; i < 4; i++) {
#pragma unroll
        for (int r = 0; r < 4; r++) {
            size_t row = (size_t)m0 + wm * 64 + i * 16 + q * 4 + r;
#pragma unroll
            for (int j = 0; j < 4; j++) {
                int col = n0 + wn * 64 + j * 16 + ml;
                float v = acc[i][j][r];
                if (EPI == 0) {
                    C[row * N + col] = v;
                } else if (EPI == 1) {
                    C[row * N + col] += v + bias[col];
                } else {
                    Cb[row * N + col] = f2bf(gelu_f(v + bias[col]));
                }
            }
        }
    }
}

// ---------------- fp32 VALU GEMM (kept for final fc, N=32) ----------------
template <int DOACC, int DOGELU>
__global__ __launch_bounds__(256) void gemm_kernel(const float* __restrict__ A,
                                                   const float* __restrict__ B,
                                                   const float* __restrict__ bias,
                                                   float* __restrict__ C,
                                                   int M, int N, int K) {
    __shared__ float As[16][132];
    __shared__ float Bs[16][132];
    int t = threadIdx.x;
    int tx = t & 15, ty = t >> 4;
    int m0 = blockIdx.x * 128;
    int n0 = blockIdx.y * 128;
    float c[8][8];
#pragma unroll
    for (int i = 0; i < 8; i++)
#pragma unroll
        for (int j = 0; j < 8; j++) c[i][j] = 0.f;
    int am = t >> 1;
    int ak = (t & 1) * 8;
    const float* Aptr = A + (size_t)(m0 + am) * K + ak;
    int bn = (t & 15) * 8;
    int bk = t >> 4;
    bool bvalid = (n0 + bn) < N;
    const float* Bptr = B + (size_t)bk * N + n0 + bn;
    for (int k0 = 0; k0 < K; k0 += 16) {
        float4 a0 = *(const float4*)(Aptr + k0);
        float4 a1 = *(const float4*)(Aptr + k0 + 4);
        As[ak + 0][am] = a0.x; As[ak + 1][am] = a0.y;
        As[ak + 2][am] = a0.z; As[ak + 3][am] = a0.w;
        As[ak + 4][am] = a1.x; As[ak + 5][am] = a1.y;
        As[ak + 6][am] = a1.z; As[ak + 7][am] = a1.w;
        float4 b0 = make_float4(0.f, 0.f, 0.f, 0.f);
        float4 b1v = make_float4(0.f, 0.f, 0.f, 0.f);
        if (bvalid) {
            const float* bp = Bptr + (size_t)k0 * N;
            b0 = *(const float4*)bp;
            b1v = *(const float4*)(bp + 4);
        }
        *(float4*)&Bs[bk][bn] = b0;
        *(float4*)&Bs[bk][bn + 4] = b1v;
        __syncthreads();
#pragma unroll
        for (int kk = 0; kk < 16; kk++) {
            float4 av0 = *(const float4*)&As[kk][ty * 4];
            float4 av1 = *(const float4*)&As[kk][64 + ty * 4];
            float4 bv0 = *(const float4*)&Bs[kk][tx * 4];
            float4 bv1 = *(const float4*)&Bs[kk][64 + tx * 4];
            float a_[8] = {av0.x, av0.y, av0.z, av0.w, av1.x, av1.y, av1.z, av1.w};
            float b_[8] = {bv0.x, bv0.y, bv0.z, bv0.w, bv1.x, bv1.y, bv1.z, bv1.w};
#pragma unroll
            for (int i = 0; i < 8; i++)
#pragma unroll
                for (int j = 0; j < 8; j++) c[i][j] += a_[i] * b_[j];
        }
        __syncthreads();
    }
#pragma unroll
    for (int ih = 0; ih < 2; ih++)
#pragma unroll
        for (int il = 0; il < 4; il++) {
            size_t row = (size_t)m0 + ih * 64 + ty * 4 + il;
#pragma unroll
            for (int jh = 0; jh < 2; jh++) {
                int colbase = n0 + jh * 64 + tx * 4;
                if (colbase < N) {
                    float* cp = C + row * N + colbase;
#pragma unroll
                    for (int jl = 0; jl < 4; jl++) {
                        float v = c[ih * 4 + il][jh * 4 + jl];
                        if (bias) v += bias[colbase + jl];
                        if (DOGELU) v = gelu_f(v);
                        if (DOACC) v += cp[jl];
                        cp[jl] = v;
                    }
                }
            }
        }
}

// ---------------- global max over key features ----------------
__global__ __launch_bounds__(320) void kmax_kernel(const float* __restrict__ Kf,
                                                   const float* __restrict__ proj,
                                                   unsigned int* __restrict__ kmaxkey,
                                                   int rows_per_block) {
    int tid = threadIdx.x;
    float4 pr[16];
    if (tid < NB) {
#pragma unroll
        for (int j = 0; j < 16; j++) pr[j] = ((const float4*)proj)[tid * 16 + j];
    }
    float lmax = -3.0e38f;
    size_t r0 = (size_t)blockIdx.x * rows_per_block;
    for (int r = 0; r < rows_per_block; r++) {
        const float4* kr = (const float4*)(Kf + (r0 + r) * DHE);
        if (tid < NB) {
            float acc = 0.f;
#pragma unroll
            for (int j = 0; j < 16; j++) {
                float4 kv = kr[j];
                acc += kv.x * pr[j].x + kv.y * pr[j].y + kv.z * pr[j].z + kv.w * pr[j].w;
            }
            lmax = fmaxf(lmax, acc);
        }
    }
    lmax *= DN_F;
#pragma unroll
    for (int off = 32; off; off >>= 1) lmax = fmaxf(lmax, __shfl_xor(lmax, off));
    __shared__ float wmax[5];
    if ((tid & 63) == 0) wmax[tid >> 6] = lmax;
    __syncthreads();
    if (tid == 0) {
        float bm = wmax[0];
        for (int w = 1; w < 5; w++) bm = fmaxf(bm, wmax[w]);
        atomicMax(kmaxkey, fkey(bm));
    }
}

// ------------- fused kp + ctx/ksum accumulation (per batch element) -------------
__global__ __launch_bounds__(320) void ctx_kernel(const float* __restrict__ Kf,
                                                  const float* __restrict__ Vf,
                                                  const float* __restrict__ proj,
                                                  const unsigned int* __restrict__ kmaxkey,
                                                  float* __restrict__ CTX,
                                                  float* __restrict__ KSUM,
                                                  int chunks) {
    __shared__ float kps[NB];
    __shared__ float vrow[DHE];
    int tid = threadIdx.x;
    int h = blockIdx.x / chunks;
    int ch = blockIdx.x - h * chunks;
    float4 pr[16];
    if (tid < NB) {
#pragma unroll
        for (int j = 0; j < 16; j++) pr[j] = ((const float4*)proj)[tid * 16 + j];
    }
    float mx = funkey(*kmaxkey);
    float cacc[54];
#pragma unroll
    for (int k = 0; k < 54; k++) cacc[k] = 0.f;
    float ksum_r = 0.f;
    int w = tid >> 6, d = tid & 63;
    int ntk = SEQ / chunks;
    int nbase = ch * ntk;
    for (int n = 0; n < ntk; n++) {
        size_t tg = (size_t)(nbase + n);
        const float4* kr = (const float4*)(Kf + tg * DIMX + h * DHE);
        if (tid < NB) {
            float acc = 0.f, ss = 0.f;
#pragma unroll
            for (int j = 0; j < 16; j++) {
                float4 kv = kr[j];
                acc += kv.x * pr[j].x + kv.y * pr[j].y + kv.z * pr[j].z + kv.w * pr[j].w;
                ss += kv.x * kv.x + kv.y * kv.y + kv.z * kv.z + kv.w * kv.w;
            }
            float kp = RATIO_F * (expf(acc * DN_F - ss * 0.0625f - mx) + 1e-4f);
            kps[tid] = kp;
            ksum_r += kp;
        }
        if (tid < 16)
            ((float4*)vrow)[tid] = ((const float4*)(Vf + tg * DIMX + h * DHE))[tid];
        __syncthreads();
        float vv = vrow[d];
#pragma unroll
        for (int k = 0; k < 54; k++) {
            int m = w + 5 * k;
            if (m < NB) cacc[k] += kps[m] * vv;
        }
        __syncthreads();
    }
    float* ctxp = CTX + (size_t)h * (NB * DHE);
#pragma unroll
    for (int k = 0; k < 54; k++) {
        int m = w + 5 * k;
        if (m < NB) atomicAdd(&ctxp[m * DHE + d], cacc[k]);
    }
    if (tid < NB) atomicAdd(&KSUM[(size_t)h * NB + tid], ksum_r);
}

// ------------- fused qp + o = d_inv * (qp @ ctx); bf16 output -------------
__global__ __launch_bounds__(320) void o_kernel(const float* __restrict__ Qf,
                                                const float* __restrict__ proj,
                                                const float* __restrict__ CTX,
                                                const float* __restrict__ KSUM,
                                                ushort_t* __restrict__ Of,
                                                int chunks) {
    __shared__ float qps[NB];
    __shared__ float redm[5];
    __shared__ float reds[5];
    __shared__ float opart[5][DHE];
    int tid = threadIdx.x;
    int h = blockIdx.x / chunks;
    int ch = blockIdx.x - h * chunks;
    float4 pr[16];
    if (tid < NB) {
#pragma unroll
        for (int j = 0; j < 16; j++) pr[j] = ((const float4*)proj)[tid * 16 + j];
    }
    int w = tid >> 6, d = tid & 63;
    float creg[54];
#pragma unroll
    for (int k = 0; k < 54; k++) {
        int m = w + 5 * k;
        creg[k] = (m < NB) ? CTX[(size_t)h * (NB * DHE) + m * DHE + d] : 0.f;
    }
    float ksum_r = (tid < NB) ? KSUM[(size_t)h * NB + tid] : 0.f;
    int ntk = SEQ / chunks;
    int nbase = ch * ntk;
    for (int n = 0; n < ntk; n++) {
        size_t tg = (size_t)(nbase + n);
        const float4* qr = (const float4*)(Qf + tg * DIMX + h * DHE);
        float xp = -3.0e38f, ss = 0.f;
        if (tid < NB) {
            float acc = 0.f;
#pragma unroll
            for (int j = 0; j < 16; j++) {
                float4 qv = qr[j];
                acc += qv.x * pr[j].x + qv.y * pr[j].y + qv.z * pr[j].z + qv.w * pr[j].w;
                ss += qv.x * qv.x + qv.y * qv.y + qv.z * qv.z + qv.w * qv.w;
            }
            xp = acc * DN_F;
        }
        float lm = xp;
#pragma unroll
        for (int off = 32; off; off >>= 1) lm = fmaxf(lm, __shfl_xor(lm, off));
        if ((tid & 63) == 0) redm[w] = lm;
        __syncthreads();
        float rmax = fmaxf(fmaxf(fmaxf(redm[0], redm[1]), fmaxf(redm[2], redm[3])), redm[4]);
        float dp = 0.f;
        if (tid < NB) {
            float qp = RATIO_F * (expf(xp - ss * 0.0625f - rmax) + 1e-4f);
            qps[tid] = qp;
            dp = qp * ksum_r;
        }
#pragma unroll
        for (int off = 32; off; off >>= 1) dp += __shfl_xor(dp, off);
        if ((tid & 63) == 0) reds[w] = dp;
        __syncthreads();
        float denom = reds[0] + reds[1] + reds[2] + reds[3] + reds[4];
        float dinv = 1.0f / denom;
        float op = 0.f;
#pragma unroll
        for (int k = 0; k < 54; k++) {
            int m = w + 5 * k;
            if (m < NB) op += qps[m] * creg[k];
        }
        opart[w][d] = op;
        __syncthreads();
        if (tid < DHE) {
            float o = opart[0][tid] + opart[1][tid] + opart[2][tid] + opart[3][tid] +
                      opart[4][tid];
            Of[tg * DIMX + h * DHE + tid] = f2bf(o * dinv);
        }
        __syncthreads();
    }
}

extern "C" void kernel_launch(void* const* d_in, const int* in_sizes, int n_in,
                              void* d_out, int out_size, void* d_ws, size_t ws_size,
                              hipStream_t stream) {
    (void)in_sizes; (void)n_in; (void)out_size; (void)ws_size;
    const float* src  = (const float*)d_in[0];
    const float* proj = (const float*)d_in[1];
    const float* ln1g = (const float*)d_in[2];
    const float* ln1b = (const float*)d_in[3];
    const float* Wq   = (const float*)d_in[4];
    const float* Wk   = (const float*)d_in[5];
    const float* Wv   = (const float*)d_in[6];
    const float* Wo   = (const float*)d_in[7];
    const float* bo   = (const float*)d_in[8];
    const float* ln2g = (const float*)d_in[9];
    const float* ln2b = (const float*)d_in[10];
    const float* W1   = (const float*)d_in[11];
    const float* b1   = (const float*)d_in[12];
    const float* W2   = (const float*)d_in[13];
    const float* b2   = (const float*)d_in[14];
    const float* fcw  = (const float*)d_in[15];
    const float* fcb  = (const float*)d_in[16];
    float* out = (float*)d_out;

    // Workspace layout (~151 MiB; 162 known-safe)
    const size_t TD = (size_t)NTOK * DIMX;
    const size_t SD = (size_t)SEQ * DIMX;
    float* X     = (float*)d_ws;              // 64 MiB residual fp32
    float* P1    = X + TD;                    // 16 MiB per-b fp32 (K, then Q)
    float* P2    = P1 + SD;                   // 16 MiB per-b fp32 (V, scratch)
    float* CTXb  = P2 + SD;                   // 8*266*64 fp32
    float* KSUMb = CTXb + NHEADS * NB * DHE;  // 8*266
    unsigned int* KMAX = (unsigned int*)(KSUMb + NHEADS * NB);
    ushort_t* Hs  = (ushort_t*)(KMAX + 4);    // 8 MiB per-b LN out bf16
    ushort_t* Ob  = Hs + SD;                  // 8 MiB per-b attn out bf16
    ushort_t* Hid = Ob + SD;                  // 32 MiB per-b FF hidden bf16
    ushort_t* Wtb = Hid + (size_t)SEQ * FFD;  // 6 MiB per-layer weights bf16 (transposed)
    ushort_t* Wqt = Wtb;
    ushort_t* Wkt = Wqt + DIMX * DIMX;
    ushort_t* Wvt = Wkt + DIMX * DIMX;
    ushort_t* Wot = Wvt + DIMX * DIMX;
    ushort_t* W1t = Wot + DIMX * DIMX;        // [FFD, DIMX]
    ushort_t* W2t = W1t + (size_t)DIMX * FFD; // [DIMX, FFD]
    const int nzero = NHEADS * NB * DHE + NHEADS * NB;

    hipMemcpyAsync(X, src, sizeof(float) * TD, hipMemcpyDeviceToDevice, stream);

    dim3 gP(SEQ / 128, DIMX / 128);   // (64,4) M=8192,N=512
    dim3 gF1(SEQ / 128, FFD / 128);   // (64,16)
    for (int L = 0; L < NLAYER; L++) {
        const float* pj = proj + (size_t)L * NB * DHE;
        // --- per-layer weight transpose-convert to bf16 ---
        wconv_kernel<<<dim3(16, 16), 256, 0, stream>>>(Wq + (size_t)L * DIMX * DIMX, Wqt, DIMX, DIMX);
        wconv_kernel<<<dim3(16, 16), 256, 0, stream>>>(Wk + (size_t)L * DIMX * DIMX, Wkt, DIMX, DIMX);
        wconv_kernel<<<dim3(16, 16), 256, 0, stream>>>(Wv + (size_t)L * DIMX * DIMX, Wvt, DIMX, DIMX);
        wconv_kernel<<<dim3(16, 16), 256, 0, stream>>>(Wo + (size_t)L * DIMX * DIMX, Wot, DIMX, DIMX);
        wconv_kernel<<<dim3(64, 16), 256, 0, stream>>>(W1 + (size_t)L * DIMX * FFD, W1t, DIMX, FFD);
        wconv_kernel<<<dim3(16, 64), 256, 0, stream>>>(W2 + (size_t)L * FFD * DIMX, W2t, FFD, DIMX);
        zero_kernel<<<1, 256, 0, stream>>>((float*)KMAX, 1);
        // --- pass 1: K per b -> global key max ---
        for (int b = 0; b < BATCH; b++) {
            const float* Xb = X + (size_t)b * SD;
            ln_bf16_kernel<<<SEQ / 4, 256, 0, stream>>>(Xb, ln1g + L * DIMX, ln1b + L * DIMX, Hs);
            gemm_mfma<0><<<gP, 256, 0, stream>>>(Hs, Wkt, nullptr, P1, nullptr, SEQ, DIMX, DIMX);
            kmax_kernel<<<1024, 320, 0, stream>>>(P1, pj, KMAX, (SEQ * NHEADS) / 1024);
        }
        // --- pass 2: per-b attention + Wo ---
        for (int b = 0; b < BATCH; b++) {
            float* Xb = X + (size_t)b * SD;
            ln_bf16_kernel<<<SEQ / 4, 256, 0, stream>>>(Xb, ln1g + L * DIMX, ln1b + L * DIMX, Hs);
            gemm_mfma<0><<<gP, 256, 0, stream>>>(Hs, Wkt, nullptr, P1, nullptr, SEQ, DIMX, DIMX);
            gemm_mfma<0><<<gP, 256, 0, stream>>>(Hs, Wvt, nullptr, P2, nullptr, SEQ, DIMX, DIMX);
            zero_kernel<<<(nzero + 255) / 256, 256, 0, stream>>>(CTXb, nzero);
            ctx_kernel<<<NHEADS * 32, 320, 0, stream>>>(P1, P2, pj, KMAX, CTXb, KSUMb, 32);
            gemm_mfma<0><<<gP, 256, 0, stream>>>(Hs, Wqt, nullptr, P2, nullptr, SEQ, DIMX, DIMX);
            o_kernel<<<NHEADS * 32, 320, 0, stream>>>(P2, pj, CTXb, KSUMb, Ob, 32);
            gemm_mfma<1><<<gP, 256, 0, stream>>>(Ob, Wot, bo + L * DIMX, Xb, nullptr, SEQ, DIMX, DIMX);
            // --- FF ---
            ln_bf16_kernel<<<SEQ / 4, 256, 0, stream>>>(Xb, ln2g + L * DIMX, ln2b + L * DIMX, Hs);
            gemm_mfma<2><<<gF1, 256, 0, stream>>>(Hs, W1t, b1 + L * FFD, nullptr, Hid, SEQ, FFD, DIMX);
            gemm_mfma<1><<<gP, 256, 0, stream>>>(Hid, W2t, b2 + L * DIMX, Xb, nullptr, SEQ, DIMX, FFD);
        }
    }
    gemm_kernel<0, 0><<<dim3(NTOK / 128, 1), 256, 0, stream>>>(X, fcw, fcb, out, NTOK, OUTD, DIMX);
}